// Round 15
// baseline (177.709 us; speedup 1.0000x reference)
//
#include <hip/hip_runtime.h>
#include <hip/hip_fp16.h>

typedef unsigned short u16;
typedef __bf16 bf16x8 __attribute__((ext_vector_type(8)));
typedef float f32x4 __attribute__((ext_vector_type(4)));

#define SCALE 0.17677669529663687f
#define LOG2E 1.4426950408889634f
#define SCALE2 (0.17677669529663687f * 1.4426950408889634f)

__device__ __forceinline__ float bf2f(u16 u) {
  union { unsigned int i; float f; } x; x.i = ((unsigned int)u) << 16; return x.f;
}
__device__ __forceinline__ u16 f2bf(float f) {
  union { __bf16 h; u16 u; } x; x.h = (__bf16)f; return x.u;
}
__device__ __forceinline__ u16 f2h(float f) {
  union { __half h; u16 u; } x; x.h = __float2half(f); return x.u;
}
__device__ __forceinline__ float fexp2(float x) {
#if __has_builtin(__builtin_amdgcn_exp2f)
  return __builtin_amdgcn_exp2f(x);
#else
  return exp2f(x);
#endif
}
__device__ __forceinline__ uint4 pack8(const u16* h) {
  uint4 r;
  r.x = (unsigned)h[0] | ((unsigned)h[1] << 16);
  r.y = (unsigned)h[2] | ((unsigned)h[3] << 16);
  r.z = (unsigned)h[4] | ((unsigned)h[5] << 16);
  r.w = (unsigned)h[6] | ((unsigned)h[7] << 16);
  return r;
}
__device__ __forceinline__ uint2 pk4(float a, float b, float c, float d) {
  uint2 r;
  r.x = (unsigned)f2bf(a) | ((unsigned)f2bf(b) << 16);
  r.y = (unsigned)f2bf(c) | ((unsigned)f2bf(d) << 16);
  return r;
}
__device__ __forceinline__ bf16x8 zfrag() {
  bf16x8 z;
  #pragma unroll
  for (int j = 0; j < 8; ++j) z[j] = (__bf16)0.0f;
  return z;
}
__device__ __forceinline__ uint2 shfl_u2(uint2 v, int src) {
  uint2 r;
  r.x = (unsigned)__shfl((int)v.x, src);
  r.y = (unsigned)__shfl((int)v.y, src);
  return r;
}

#define LSTR 72   // proj GEMM LDS row stride in ushorts (144B, b128-aligned)
#define ASTR 200  // qkv GEMM LDS row stride in ushorts

// ---------------------------------------------------------------------------
// qkv GEMM (og-split + XCD-coherent dispatch order):
// idx = (mt%8) + 8*(og + 3*(mt/8)) keeps the 3 og-peers of a panel on the
// same XCD and within 24 dispatch slots -> x panel L2-resident across peers.
// ---------------------------------------------------------------------------
__global__ __launch_bounds__(256) void k_qkv(
    const float* __restrict__ Ag, const u16* __restrict__ Wq, const float* __restrict__ biasg,
    u16* __restrict__ qo, u16* __restrict__ ko, u16* __restrict__ vo)
{
  __shared__ __align__(16) u16 As[64 * ASTR];
  __shared__ __align__(16) u16 Bs[64 * ASTR];
  const int idx = blockIdx.x;
  const int og = (idx >> 3) % 3;
  const int mt = (idx & 7) + 8 * (idx / 24);
  const int tid = threadIdx.x, lane = tid & 63, wid = tid >> 6;
  const int wt = wid >> 1, wc = wid & 1;
  const int lm = lane & 15, kg = lane >> 4;

  #pragma unroll
  for (int i = 0; i < 6; ++i) {
    int c = tid + i * 256;
    int row = c / 24, cc = (c % 24) * 8;
    const float* s = Ag + (size_t)(mt * 64 + row) * 192 + cc;
    float f[8];
    *(float4*)f = *(const float4*)s;
    *(float4*)(f + 4) = *(const float4*)(s + 4);
    u16 h[8];
    #pragma unroll
    for (int j = 0; j < 8; ++j) h[j] = f2bf(f[j]);
    *(uint4*)(As + row * ASTR + cc) = pack8(h);
  }

  u16* const dst = (og == 0) ? qo : (og == 1) ? ko : vo;

  for (int nt = 0; nt < 3; ++nt) {
    __syncthreads();
    #pragma unroll
    for (int i = 0; i < 6; ++i) {
      int c = tid + i * 256;
      int row = c / 24, cc = (c % 24) * 8;
      *(uint4*)(Bs + row * ASTR + cc) =
          *(const uint4*)(Wq + (size_t)(og * 192 + nt * 64 + row) * 192 + cc);
    }
    __syncthreads();

    f32x4 acc[2][2] = {};   // [cf][tf]
    #pragma unroll
    for (int ks = 0; ks < 6; ++ks) {
      bf16x8 xfr[2];
      #pragma unroll
      for (int tf = 0; tf < 2; ++tf)
        xfr[tf] = *(const bf16x8*)(As + (wt * 32 + tf * 16 + lm) * ASTR + ks * 32 + kg * 8);
      #pragma unroll
      for (int cf = 0; cf < 2; ++cf) {
        bf16x8 wfr = *(const bf16x8*)(Bs + (wc * 32 + cf * 16 + lm) * ASTR + ks * 32 + kg * 8);
        #pragma unroll
        for (int tf = 0; tf < 2; ++tf)
          acc[cf][tf] = __builtin_amdgcn_mfma_f32_16x16x32_bf16(wfr, xfr[tf], acc[cf][tf], 0, 0, 0);
      }
    }

    #pragma unroll
    for (int cf = 0; cf < 2; ++cf) {
      int cc = nt * 64 + wc * 32 + cf * 16 + kg * 4;
      int hh = cc >> 5, dd = cc & 31;
      f32x4 bv = *(const f32x4*)(biasg + og * 192 + cc);
      #pragma unroll
      for (int tf = 0; tf < 2; ++tf) {
        int tg = mt * 64 + wt * 32 + tf * 16 + lm;
        int bq = tg / 196, tok = tg - bq * 196;
        *(uint2*)(dst + (((size_t)bq * 6 + hh) * 196 + tok) * 32 + dd) =
            pk4(acc[cf][tf][0] + bv[0], acc[cf][tf][1] + bv[1],
                acc[cf][tf][2] + bv[2], acc[cf][tf][3] + bv[3]);
      }
    }
  }
}

// ---------------------------------------------------------------------------
// proj GEMM: LDS-staged A + Bh/Bl copied from precomputed wph/wpl.
// ---------------------------------------------------------------------------
__global__ __launch_bounds__(256) void k_proj(
    const u16* __restrict__ Ag, const u16* __restrict__ Wh, const u16* __restrict__ Wl,
    const float* __restrict__ biasg, float* __restrict__ og)
{
  __shared__ __align__(16) u16 As[128 * LSTR];
  __shared__ __align__(16) u16 Bh[64 * LSTR];
  __shared__ __align__(16) u16 Bl[64 * LSTR];
  const int mt = blockIdx.x / 3, nt = blockIdx.x % 3;
  const int tid = threadIdx.x, lane = tid & 63, wid = tid >> 6;
  const int wm = wid >> 1, wn = wid & 1;
  const int lm = lane & 15, kg = lane >> 4;

  f32x4 acc[4][2] = {};
  const int aoffbase = (wm * 64 + lm) * LSTR + kg * 8;
  const int boffbase = (wn * 32 + lm) * LSTR + kg * 8;

  for (int kt = 0; kt < 3; ++kt) {
    #pragma unroll
    for (int i = 0; i < 4; ++i) {
      int c = tid + i * 256;
      int row = c >> 3, cc = (c & 7) * 8;
      *(uint4*)(As + row * LSTR + cc) =
          *(const uint4*)(Ag + (size_t)(mt * 128 + row) * 192 + kt * 64 + cc);
    }
    #pragma unroll
    for (int i = 0; i < 2; ++i) {
      int c = tid + i * 256;
      int row = c >> 3, cc = (c & 7) * 8;
      size_t src = (size_t)(nt * 64 + row) * 192 + kt * 64 + cc;
      *(uint4*)(Bh + row * LSTR + cc) = *(const uint4*)(Wh + src);
      *(uint4*)(Bl + row * LSTR + cc) = *(const uint4*)(Wl + src);
    }
    __syncthreads();
    #pragma unroll
    for (int ks = 0; ks < 2; ++ks) {
      bf16x8 bh_[2], bl_[2];
      #pragma unroll
      for (int nf = 0; nf < 2; ++nf) {
        bh_[nf] = *(const bf16x8*)(Bh + boffbase + nf * 16 * LSTR + ks * 32);
        bl_[nf] = *(const bf16x8*)(Bl + boffbase + nf * 16 * LSTR + ks * 32);
      }
      #pragma unroll
      for (int mf = 0; mf < 4; ++mf) {
        bf16x8 af = *(const bf16x8*)(As + aoffbase + mf * 16 * LSTR + ks * 32);
        #pragma unroll
        for (int nf = 0; nf < 2; ++nf) {
          acc[mf][nf] = __builtin_amdgcn_mfma_f32_16x16x32_bf16(af, bh_[nf], acc[mf][nf], 0, 0, 0);
          acc[mf][nf] = __builtin_amdgcn_mfma_f32_16x16x32_bf16(af, bl_[nf], acc[mf][nf], 0, 0, 0);
        }
      }
    }
    __syncthreads();
  }

  #pragma unroll
  for (int mf = 0; mf < 4; ++mf) {
    int m0 = mt * 128 + wm * 64 + mf * 16 + kg * 4;
    #pragma unroll
    for (int nf = 0; nf < 2; ++nf) {
      int col = nt * 64 + wn * 32 + nf * 16 + lm;
      float bias = biasg[col];
      #pragma unroll
      for (int r = 0; r < 4; ++r)
        og[(size_t)(m0 + r) * 192 + col] = acc[mf][nf][r] + bias;
    }
  }
}

// ---------------------------------------------------------------------------
// bias precompute (pre-scaled by LOG2E) + qkv_w f32->bf16 + proj_w hi/lo
// ---------------------------------------------------------------------------
__device__ __forceinline__ void lerpw(int i, int& j0, int& j1, float& f) {
  float xx = 0.5f * i - 0.25f;
  int j = (int)floorf(xx);
  f = xx - j;
  if (j < 0) { j = 0; f = 0.f; }
  j0 = j;
  j1 = (j + 1 > 6) ? 6 : j + 1;
}
__device__ __forceinline__ float bilin7(const float* src, int y, int x) {
  int y0, y1, x0, x1; float fy, fx;
  lerpw(y, y0, y1, fy); lerpw(x, x0, x1, fx);
  float v00 = src[y0 * 7 + x0], v01 = src[y0 * 7 + x1];
  float v10 = src[y1 * 7 + x0], v11 = src[y1 * 7 + x1];
  return (1.f - fy) * ((1.f - fx) * v00 + fx * v01) + fy * ((1.f - fx) * v10 + fx * v11);
}
__global__ __launch_bounds__(256) void k_bias(
    const float* __restrict__ an_, const float* __restrict__ na_,
    const float* __restrict__ ah_, const float* __restrict__ aw_,
    const float* __restrict__ ha_, const float* __restrict__ wa_,
    const float* __restrict__ qw_, const float* __restrict__ pw_,
    float* __restrict__ b1, float* __restrict__ b2, u16* __restrict__ wq,
    u16* __restrict__ wph, u16* __restrict__ wpl)
{
  int i = blockIdx.x * 256 + threadIdx.x;
  const int T1 = 6 * 49 * 208;
  const int T2 = 6 * 196 * 64;
  const int T3 = 576 * 192;
  const int T4 = 192 * 192;
  if (i < T1) {
    int n = i % 208, a = (i / 208) % 49, h = i / (208 * 49);
    float v = 0.f;
    if (n < 196) {
      int y = n / 14, x = n - y * 14;
      v = bilin7(an_ + (h * 49 + a) * 49, y, x)
        + ah_[(h * 49 + a) * 14 + y] + aw_[(h * 49 + a) * 14 + x];
    }
    b1[i] = v * LOG2E;
  } else if (i < T1 + T2) {
    int j = i - T1;
    int a = j & 63, n = (j >> 6) % 196, h = j / (196 * 64);
    float v = 0.f;
    if (a < 49) {
      int y = n / 14, x = n - y * 14;
      v = bilin7(na_ + (h * 49 + a) * 49, y, x)
        + ha_[(h * 14 + y) * 49 + a] + wa_[(h * 14 + x) * 49 + a];
    }
    b2[j] = v * LOG2E;
  } else if (i < T1 + T2 + T3) {
    int j = i - T1 - T2;
    wq[j] = f2bf(qw_[j]);
  } else if (i < T1 + T2 + T3 + T4) {
    int j = i - T1 - T2 - T3;
    float w = pw_[j];
    u16 hi = f2bf(w);
    wph[j] = hi;
    wpl[j] = f2bf(w - bf2f(hi));
  }
}

// ---------------------------------------------------------------------------
// MFMA attention + fused agent-pooling + fused depthwise conv.
// NEW: k_pool is fused in — Q is staged to LDS (qrm) alongside V, agent
// tokens pooled in-LDS (agl) before p1. Removes the k_pool dispatch and
// ~48 MB of HBM round-trip (q re-read + ag write/read).
// LDS: vtbuf 13.9K ∪ avt, vrm 15.7K, qrm 15.7K, agl 3.1K, wdl 1.3K = 49.7 KB.
// ---------------------------------------------------------------------------
#define VTSTR 216 // vt row stride in u16 (432B; +skew (d>>3)*16, rows never overlap)
#define QSTR 72   // avt row stride
#define VSTR 40   // vrm/qrm row stride in u16 (80B, 16B-aligned rows)

__global__ __launch_bounds__(256, 4) void k_attn(
    const u16* __restrict__ qg, const u16* __restrict__ kgl, const u16* __restrict__ vgl,
    const float* __restrict__ b1p, const float* __restrict__ b2p,
    const float* __restrict__ dwcw, const float* __restrict__ dwcb,
    u16* __restrict__ preg)
{
  __shared__ __align__(16) u16 vtbuf[6976];      // 13952 B : vt (skewed) ∪ avt[32*QSTR]
  __shared__ __align__(16) u16 vrm[196 * VSTR];  // 15680 B : V [n][d] as f16
  __shared__ __align__(16) u16 qrm[196 * VSTR];  // 15680 B : Q [n][d] bf16
  __shared__ __align__(16) u16 agl[49 * 32];     //  3136 B : pooled agent tokens bf16
  __shared__ __align__(16) float wdl[320];       //  1280 B : [tap][32] weights + [32] bias

  u16* const vt = vtbuf;
  u16* const avt = vtbuf;   // reused after p2 (guarded by barrier)

  const int bh = blockIdx.x, h = bh % 6, b = bh / 6;
  const int tid = threadIdx.x, lane = tid & 63, w = tid >> 6;
  const int lm = lane & 15, kg = lane >> 4;
  const size_t base = (size_t)bh * (196 * 32);

  // ---- stage V (vt skewed bf16 + vrm f16) and Q (qrm bf16) ----
  for (int c = tid; c < 784; c += 256) {
    int row = c >> 2, d0 = (c & 3) * 8;
    uint4 vv = *(const uint4*)(vgl + base + row * 32 + d0);
    uint4 qv = *(const uint4*)(qg + base + row * 32 + d0);
    *(uint4*)(qrm + row * VSTR + d0) = qv;
    const u16* pv = (const u16*)&vv;
    u16 hf[8];
    int tb = d0 * VTSTR + (d0 >> 3) * 16 + row;
    #pragma unroll
    for (int j = 0; j < 8; ++j) {
      vt[tb + j * VTSTR] = pv[j];
      hf[j] = f2h(bf2f(pv[j]));
    }
    *(uint4*)(vrm + row * VSTR + d0) = pack8(hf);
  }
  // zero vt cols 196..207 of each of 32 d rows (skewed addresses)
  for (int c = tid; c < 384; c += 256) {
    int d = c / 12, n = 196 + c % 12;
    vt[d * VTSTR + (d >> 3) * 16 + n] = 0;
  }
  // conv weights, transposed layout: wdl[tap*32 + d] ; bias at wdl[288 + d]
  for (int c = tid; c < 320; c += 256) {
    if (c < 288) {
      int tap = c >> 5, d = c & 31;
      wdl[tap * 32 + d] = dwcw[h * 288 + d * 9 + tap];
    } else {
      wdl[c] = dwcb[h * 32 + (c - 288)];
    }
  }

  const int arow = 16 * w + lm;

  // ---- b1 bias PREFETCH (global-only; flies across the barriers) ----
  f32x4 b1v[13];
  {
    const float* b1base = b1p + ((size_t)(h * 49 + arow) * 208 + 4 * kg);
    #pragma unroll
    for (int t = 0; t < 13; ++t)
      b1v[t] = (arow < 49) ? *(const f32x4*)(b1base + 16 * t) : (f32x4){0.f, 0.f, 0.f, 0.f};
  }

  __syncthreads();   // bar0: qrm (and vt/vrm/wdl) staged

  // ---- fused agent pooling: 2x2 avg of qrm -> agl (threads 0..195) ----
  if (tid < 196) {
    int a = tid >> 2, d8 = tid & 3;
    int py = a / 7, px = a - py * 7;
    int n0 = (py * 2) * 14 + px * 2;
    const u16* q0 = qrm + n0 * VSTR + d8 * 8;
    uint4 r0 = *(const uint4*)(q0);
    uint4 r1 = *(const uint4*)(q0 + VSTR);
    uint4 r2 = *(const uint4*)(q0 + 14 * VSTR);
    uint4 r3 = *(const uint4*)(q0 + 15 * VSTR);
    const u16 *p0 = (const u16*)&r0, *p1 = (const u16*)&r1, *p2 = (const u16*)&r2, *p3 = (const u16*)&r3;
    u16 o[8];
    #pragma unroll
    for (int j = 0; j < 8; ++j)
      o[j] = f2bf(0.25f * (bf2f(p0[j]) + bf2f(p1[j]) + bf2f(p2[j]) + bf2f(p3[j])));
    *(uint4*)(agl + a * 32 + d8 * 8) = pack8(o);
  }

  __syncthreads();   // bar1: agl ready

  // ---- ag fragment for p1 ----
  bf16x8 agw;
  agw = (arow < 49) ? *(const bf16x8*)(agl + arow * 32 + kg * 8) : zfrag();

  // ---- p1: S1[n][a] via direct-global K fragments ----
  f32x4 acc1[13];
  #pragma unroll
  for (int t = 0; t < 13; ++t) {
    bf16x8 afr = *(const bf16x8*)(kgl + base + (16 * t + lm) * 32 + kg * 8);
    acc1[t] = __builtin_amdgcn_mfma_f32_16x16x32_bf16(afr, agw, (f32x4){0.f, 0.f, 0.f, 0.f}, 0, 0, 0);
  }

  // ---- sm1: no-max exp2 softmax; pack UNNORMALIZED e ----
  uint2 p1pk[13];
  float inv1;
  {
    #pragma unroll
    for (int t = 0; t < 13; ++t) {
      #pragma unroll
      for (int r = 0; r < 4; ++r) acc1[t][r] = acc1[t][r] * SCALE2 + b1v[t][r];
    }
    float sum = 0.f;
    #pragma unroll
    for (int t = 0; t < 13; ++t) {
      #pragma unroll
      for (int r = 0; r < 4; ++r) {
        float e = (t < 12 || kg == 0) ? fexp2(acc1[t][r]) : 0.f;
        acc1[t][r] = e; sum += e;
      }
    }
    sum += __shfl_xor(sum, 16);
    sum += __shfl_xor(sum, 32);
    inv1 = 1.0f / sum;
    #pragma unroll
    for (int t = 0; t < 13; ++t)
      p1pk[t] = pk4(acc1[t][0], acc1[t][1], acc1[t][2], acc1[t][3]);
  }

  // ---- p2: AV[a][d] = sum_n P1[a][n]·V[n][d]; A-frags via intra-wave shfl ----
  f32x4 accav[2] = {{0.f, 0.f, 0.f, 0.f}, {0.f, 0.f, 0.f, 0.f}};
  const int sl = (lane & 15) | (((2 * kg) & 3) << 4);
  const int sh = (lane & 15) | (((2 * kg + 1) & 3) << 4);
  #pragma unroll
  for (int kt = 0; kt < 6; ++kt) {
    uint2 e0 = shfl_u2(p1pk[2 * kt], sl);
    uint2 e1 = shfl_u2(p1pk[2 * kt + 1], sl);
    uint2 o0 = shfl_u2(p1pk[2 * kt], sh);
    uint2 o1 = shfl_u2(p1pk[2 * kt + 1], sh);
    uint2 lo = (kg & 2) ? e1 : e0;
    uint2 hi = (kg & 2) ? o1 : o0;
    union { uint4 u; bf16x8 v; } a_;
    a_.u = make_uint4(lo.x, lo.y, hi.x, hi.y);
    #pragma unroll
    for (int nt = 0; nt < 2; ++nt) {
      const int vd = 16 * nt + lm;
      bf16x8 bfr = *(const bf16x8*)(vt + vd * VTSTR + (vd >> 3) * 16 + kt * 32 + kg * 8);
      accav[nt] = __builtin_amdgcn_mfma_f32_16x16x32_bf16(a_.v, bfr, accav[nt], 0, 0, 0);
    }
  }
  {
    union { uint4 u; bf16x8 v; } a_;
    a_.u = make_uint4(p1pk[12].x, p1pk[12].y, 0u, 0u);
    #pragma unroll
    for (int nt = 0; nt < 2; ++nt) {
      const int vd = 16 * nt + lm;
      uint2 vv = *(const uint2*)(vt + vd * VTSTR + (vd >> 3) * 16 + 192 + 4 * kg);
      union { uint4 u; bf16x8 v; } b_;
      b_.u = make_uint4(vv.x, vv.y, 0u, 0u);
      accav[nt] = __builtin_amdgcn_mfma_f32_16x16x32_bf16(a_.v, b_.v, accav[nt], 0, 0, 0);
    }
  }

  // normalize after p2: accav rows are a = 16w + 4kg + r; inv lives at lane lm=4kg+r
  float si[4];
  #pragma unroll
  for (int r = 0; r < 4; ++r) si[r] = __shfl(inv1, kg * 4 + r);

  __syncthreads();   // bar2a: ALL waves done reading vt -> safe to reuse as avt

  // AV^T to LDS (cross-wave redistribution for p4), into the vt buffer
  #pragma unroll
  for (int nt = 0; nt < 2; ++nt)
    *(uint2*)(avt + (16 * nt + lm) * QSTR + 16 * w + 4 * kg) =
        pk4(accav[nt][0] * si[0], accav[nt][1] * si[1],
            accav[nt][2] * si[2], accav[nt][3] * si[3]);

  // ---- Q and AG fragments for the i-loop (from LDS) ----
  bf16x8 qf[4];
  #pragma unroll
  for (int i = 0; i < 4; ++i) {
    int nt = w + 4 * i;
    int row = 16 * nt + lm;
    if (nt < 13 && row < 196)
      qf[i] = *(const bf16x8*)(qrm + row * VSTR + kg * 8);
    else
      qf[i] = zfrag();
  }
  bf16x8 agf[4];
  #pragma unroll
  for (int mt = 0; mt < 4; ++mt) {
    int a = 16 * mt + lm;
    if (a < 49) agf[mt] = *(const bf16x8*)(agl + a * 32 + kg * 8);
    else agf[mt] = zfrag();
  }

  __syncthreads();   // bar2: avt visible to all waves

  // ---- per n-tile: p3 (S2^T) + sm2 + shfl-exchange + p4 + dwconv + store ----
  #pragma unroll
  for (int i = 0; i < 4; ++i) {
    int nt = w + 4 * i;
    if (nt < 13) {
      const int ncol = 16 * nt + lm;
      f32x4 acc2[4];
      #pragma unroll
      for (int mt = 0; mt < 4; ++mt)
        acc2[mt] = __builtin_amdgcn_mfma_f32_16x16x32_bf16(agf[mt], qf[i], (f32x4){0.f, 0.f, 0.f, 0.f}, 0, 0, 0);
      const float* b2base = b2p + ((size_t)(h * 196 + (ncol < 196 ? ncol : 0)) * 64 + 4 * kg);
      #pragma unroll
      for (int mt = 0; mt < 4; ++mt) {
        f32x4 bv = (ncol < 196) ? *(const f32x4*)(b2base + 16 * mt) : (f32x4){0.f, 0.f, 0.f, 0.f};
        #pragma unroll
        for (int r = 0; r < 4; ++r) acc2[mt][r] = acc2[mt][r] * SCALE2 + bv[r];
      }
      float sum = 0.f;
      #pragma unroll
      for (int mt = 0; mt < 4; ++mt) {
        #pragma unroll
        for (int r = 0; r < 4; ++r) {
          bool valid = (mt < 3) || (kg == 0 && r == 0);
          float e = valid ? fexp2(acc2[mt][r]) : 0.f;
          acc2[mt][r] = e; sum += e;
        }
      }
      sum += __shfl_xor(sum, 16);
      sum += __shfl_xor(sum, 32);
      const float inv = 1.0f / sum;   // applied after p4 (lane owns ncol)
      uint2 p2pk[4];
      #pragma unroll
      for (int mt = 0; mt < 4; ++mt)
        p2pk[mt] = pk4(acc2[mt][0], acc2[mt][1], acc2[mt][2], acc2[mt][3]);

      // p4: out^T[d][ncol] = sum_a AVt[d][a]·P2[a][ncol]
      f32x4 acc4[2] = {{0.f, 0.f, 0.f, 0.f}, {0.f, 0.f, 0.f, 0.f}};
      #pragma unroll
      for (int kt = 0; kt < 2; ++kt) {
        uint2 e0 = shfl_u2(p2pk[2 * kt], sl);
        uint2 e1 = shfl_u2(p2pk[2 * kt + 1], sl);
        uint2 o0 = shfl_u2(p2pk[2 * kt], sh);
        uint2 o1 = shfl_u2(p2pk[2 * kt + 1], sh);
        uint2 lo = (kg & 2) ? e1 : e0;
        uint2 hi = (kg & 2) ? o1 : o0;
        union { uint4 u; bf16x8 v; } b_;
        b_.u = make_uint4(lo.x, lo.y, hi.x, hi.y);
        #pragma unroll
        for (int mt2 = 0; mt2 < 2; ++mt2) {
          bf16x8 afr = *(const bf16x8*)(avt + (16 * mt2 + lm) * QSTR + kt * 32 + kg * 8);
          acc4[mt2] = __builtin_amdgcn_mfma_f32_16x16x32_bf16(afr, b_.v, acc4[mt2], 0, 0, 0);
        }
      }
      if (ncol < 196) {
        // ---- fused depthwise 3x3 conv: f16 vrm reads -> fma_mix, f32 accum ----
        const int y = ncol / 14, x = ncol - y * 14;
        float dw[2][4];
        #pragma unroll
        for (int mt = 0; mt < 2; ++mt) {
          f32x4 bv = *(const f32x4*)(wdl + 288 + 16 * mt + 4 * kg);
          #pragma unroll
          for (int r = 0; r < 4; ++r) dw[mt][r] = bv[r];
        }
        #pragma unroll
        for (int ky = 0; ky < 3; ++ky) {
          int yy = y + ky - 1;
          if (yy < 0 || yy > 13) continue;
          #pragma unroll
          for (int kx = 0; kx < 3; ++kx) {
            int xx = x + kx - 1;
            if (xx < 0 || xx > 13) continue;
            int nv = yy * 14 + xx;
            int tap = ky * 3 + kx;
            #pragma unroll
            for (int mt = 0; mt < 2; ++mt) {
              f32x4 wv = *(const f32x4*)(wdl + tap * 32 + 16 * mt + 4 * kg);
              const __half2* hv = (const __half2*)(vrm + nv * VSTR + 16 * mt + 4 * kg);
              __half2 h0 = hv[0], h1 = hv[1];
              dw[mt][0] += wv[0] * __low2float(h0);
              dw[mt][1] += wv[1] * __high2float(h0);
              dw[mt][2] += wv[2] * __low2float(h1);
              dw[mt][3] += wv[3] * __high2float(h1);
            }
          }
        }
        u16* orow = preg + ((size_t)b * 196 + ncol) * 192 + h * 32;
        #pragma unroll
        for (int mt = 0; mt < 2; ++mt)
          *(uint2*)(orow + 16 * mt + 4 * kg) =
              pk4(acc4[mt][0] * inv + dw[mt][0], acc4[mt][1] * inv + dw[mt][1],
                  acc4[mt][2] * inv + dw[mt][2], acc4[mt][3] * inv + dw[mt][3]);
      }
    }
  }
}

// ---------------------------------------------------------------------------
extern "C" void kernel_launch(void* const* d_in, const int* in_sizes, int n_in,
                              void* d_out, int out_size, void* d_ws, size_t ws_size,
                              hipStream_t stream)
{
  (void)in_sizes; (void)n_in; (void)out_size;
  const float* x      = (const float*)d_in[0];
  const float* qkv_w  = (const float*)d_in[1];
  const float* qkv_b  = (const float*)d_in[2];
  const float* proj_w = (const float*)d_in[3];
  const float* proj_b = (const float*)d_in[4];
  const float* dwc_w  = (const float*)d_in[5];
  const float* dwc_b  = (const float*)d_in[6];
  const float* an_b   = (const float*)d_in[7];
  const float* na_b   = (const float*)d_in[8];
  const float* ah_b   = (const float*)d_in[9];
  const float* aw_b   = (const float*)d_in[10];
  const float* ha_b   = (const float*)d_in[11];
  const float* wa_b   = (const float*)d_in[12];

  const size_t SZ_QKV = (size_t)512 * 6 * 196 * 32 * 2;   // bf16
  const size_t SZ_AG  = (size_t)512 * 6 * 49 * 32 * 2;    // (unused, layout kept)
  const size_t SZ_B1  = (((size_t)6 * 49 * 208 * 4) + 255) & ~(size_t)255;
  const size_t SZ_B2  = (size_t)6 * 196 * 64 * 4;
  const size_t SZ_WQ  = (((size_t)576 * 192 * 2) + 255) & ~(size_t)255;
  const size_t SZ_WP  = (((size_t)192 * 192 * 2) + 255) & ~(size_t)255;

  char* ws = (char*)d_ws;
  u16*   qb    = (u16*)(ws);
  u16*   kb    = (u16*)(ws + SZ_QKV);
  u16*   vb    = (u16*)(ws + 2 * SZ_QKV);
  float* b1    = (float*)(ws + 3 * SZ_QKV + SZ_AG);
  float* b2    = (float*)(ws + 3 * SZ_QKV + SZ_AG + SZ_B1);
  u16*   preb  = (u16*)(ws + 3 * SZ_QKV + SZ_AG + SZ_B1 + SZ_B2);
  u16*   wqb   = (u16*)(ws + 3 * SZ_QKV + SZ_AG + SZ_B1 + SZ_B2 + SZ_QKV);
  u16*   wph   = (u16*)(ws + 3 * SZ_QKV + SZ_AG + SZ_B1 + SZ_B2 + SZ_QKV + SZ_WQ);
  u16*   wpl   = (u16*)(ws + 3 * SZ_QKV + SZ_AG + SZ_B1 + SZ_B2 + SZ_QKV + SZ_WQ + SZ_WP);

  const size_t need = 3 * SZ_QKV + SZ_AG + SZ_B1 + SZ_B2 + SZ_QKV + SZ_WQ + 2 * SZ_WP;
  if (ws_size < need) return;

  const int TOT = 6 * 49 * 208 + 6 * 196 * 64 + 576 * 192 + 192 * 192;
  k_bias<<<(TOT + 255) / 256, 256, 0, stream>>>(an_b, na_b, ah_b, aw_b, ha_b, wa_b,
                                                qkv_w, proj_w, b1, b2, wqb, wph, wpl);
  k_qkv<<<1568 * 3, 256, 0, stream>>>(x, wqb, qkv_b, qb, kb, vb);
  k_attn<<<3072, 256, 0, stream>>>(qb, kb, vb, b1, b2, dwc_w, dwc_b, preb);
  k_proj<<<784 * 3, 256, 0, stream>>>(preb, wph, wpl, proj_b, (float*)d_out);
}

// Round 16
// 172.845 us; speedup vs baseline: 1.0281x; 1.0281x over previous
//
#include <hip/hip_runtime.h>
#include <hip/hip_fp16.h>

typedef unsigned short u16;
typedef __bf16 bf16x8 __attribute__((ext_vector_type(8)));
typedef float f32x4 __attribute__((ext_vector_type(4)));

#define SCALE 0.17677669529663687f
#define LOG2E 1.4426950408889634f
#define SCALE2 (0.17677669529663687f * 1.4426950408889634f)

__device__ __forceinline__ float bf2f(u16 u) {
  union { unsigned int i; float f; } x; x.i = ((unsigned int)u) << 16; return x.f;
}
__device__ __forceinline__ u16 f2bf(float f) {
  union { __bf16 h; u16 u; } x; x.h = (__bf16)f; return x.u;
}
__device__ __forceinline__ u16 f2h(float f) {
  union { __half h; u16 u; } x; x.h = __float2half(f); return x.u;
}
__device__ __forceinline__ float fexp2(float x) {
#if __has_builtin(__builtin_amdgcn_exp2f)
  return __builtin_amdgcn_exp2f(x);
#else
  return exp2f(x);
#endif
}
__device__ __forceinline__ uint4 pack8(const u16* h) {
  uint4 r;
  r.x = (unsigned)h[0] | ((unsigned)h[1] << 16);
  r.y = (unsigned)h[2] | ((unsigned)h[3] << 16);
  r.z = (unsigned)h[4] | ((unsigned)h[5] << 16);
  r.w = (unsigned)h[6] | ((unsigned)h[7] << 16);
  return r;
}
__device__ __forceinline__ uint2 pk4(float a, float b, float c, float d) {
  uint2 r;
  r.x = (unsigned)f2bf(a) | ((unsigned)f2bf(b) << 16);
  r.y = (unsigned)f2bf(c) | ((unsigned)f2bf(d) << 16);
  return r;
}
__device__ __forceinline__ bf16x8 zfrag() {
  bf16x8 z;
  #pragma unroll
  for (int j = 0; j < 8; ++j) z[j] = (__bf16)0.0f;
  return z;
}
__device__ __forceinline__ uint2 shfl_u2(uint2 v, int src) {
  uint2 r;
  r.x = (unsigned)__shfl((int)v.x, src);
  r.y = (unsigned)__shfl((int)v.y, src);
  return r;
}

#define LSTR 72   // proj GEMM LDS row stride in ushorts (144B, b128-aligned)
#define ASTR 200  // qkv GEMM LDS row stride in ushorts

// ---------------------------------------------------------------------------
// qkv GEMM (round-8 form): block = (64-token panel, og). A staged once
// (f32->bf16), 3 n-tiles of 64 cols from bf16 W staged in LDS.
// Operand-swapped MFMA -> C^T, uint2 packed stores.
// ---------------------------------------------------------------------------
__global__ __launch_bounds__(256) void k_qkv(
    const float* __restrict__ Ag, const u16* __restrict__ Wq, const float* __restrict__ biasg,
    u16* __restrict__ qo, u16* __restrict__ ko, u16* __restrict__ vo)
{
  __shared__ __align__(16) u16 As[64 * ASTR];
  __shared__ __align__(16) u16 Bs[64 * ASTR];
  const int og = blockIdx.x / 1568, mt = blockIdx.x % 1568;
  const int tid = threadIdx.x, lane = tid & 63, wid = tid >> 6;
  const int wt = wid >> 1, wc = wid & 1;
  const int lm = lane & 15, kg = lane >> 4;

  #pragma unroll
  for (int i = 0; i < 6; ++i) {
    int c = tid + i * 256;
    int row = c / 24, cc = (c % 24) * 8;
    const float* s = Ag + (size_t)(mt * 64 + row) * 192 + cc;
    float f[8];
    *(float4*)f = *(const float4*)s;
    *(float4*)(f + 4) = *(const float4*)(s + 4);
    u16 h[8];
    #pragma unroll
    for (int j = 0; j < 8; ++j) h[j] = f2bf(f[j]);
    *(uint4*)(As + row * ASTR + cc) = pack8(h);
  }

  u16* const dst = (og == 0) ? qo : (og == 1) ? ko : vo;

  for (int nt = 0; nt < 3; ++nt) {
    __syncthreads();
    #pragma unroll
    for (int i = 0; i < 6; ++i) {
      int c = tid + i * 256;
      int row = c / 24, cc = (c % 24) * 8;
      *(uint4*)(Bs + row * ASTR + cc) =
          *(const uint4*)(Wq + (size_t)(og * 192 + nt * 64 + row) * 192 + cc);
    }
    __syncthreads();

    f32x4 acc[2][2] = {};   // [cf][tf]
    #pragma unroll
    for (int ks = 0; ks < 6; ++ks) {
      bf16x8 xfr[2];
      #pragma unroll
      for (int tf = 0; tf < 2; ++tf)
        xfr[tf] = *(const bf16x8*)(As + (wt * 32 + tf * 16 + lm) * ASTR + ks * 32 + kg * 8);
      #pragma unroll
      for (int cf = 0; cf < 2; ++cf) {
        bf16x8 wfr = *(const bf16x8*)(Bs + (wc * 32 + cf * 16 + lm) * ASTR + ks * 32 + kg * 8);
        #pragma unroll
        for (int tf = 0; tf < 2; ++tf)
          acc[cf][tf] = __builtin_amdgcn_mfma_f32_16x16x32_bf16(wfr, xfr[tf], acc[cf][tf], 0, 0, 0);
      }
    }

    #pragma unroll
    for (int cf = 0; cf < 2; ++cf) {
      int cc = nt * 64 + wc * 32 + cf * 16 + kg * 4;
      int hh = cc >> 5, dd = cc & 31;
      f32x4 bv = *(const f32x4*)(biasg + og * 192 + cc);
      #pragma unroll
      for (int tf = 0; tf < 2; ++tf) {
        int tg = mt * 64 + wt * 32 + tf * 16 + lm;
        int bq = tg / 196, tok = tg - bq * 196;
        *(uint2*)(dst + (((size_t)bq * 6 + hh) * 196 + tok) * 32 + dd) =
            pk4(acc[cf][tf][0] + bv[0], acc[cf][tf][1] + bv[1],
                acc[cf][tf][2] + bv[2], acc[cf][tf][3] + bv[3]);
      }
    }
  }
}

// ---------------------------------------------------------------------------
// proj GEMM: LDS-staged A + Bh/Bl copied from precomputed wph/wpl.
// ---------------------------------------------------------------------------
__global__ __launch_bounds__(256) void k_proj(
    const u16* __restrict__ Ag, const u16* __restrict__ Wh, const u16* __restrict__ Wl,
    const float* __restrict__ biasg, float* __restrict__ og)
{
  __shared__ __align__(16) u16 As[128 * LSTR];
  __shared__ __align__(16) u16 Bh[64 * LSTR];
  __shared__ __align__(16) u16 Bl[64 * LSTR];
  const int mt = blockIdx.x / 3, nt = blockIdx.x % 3;
  const int tid = threadIdx.x, lane = tid & 63, wid = tid >> 6;
  const int wm = wid >> 1, wn = wid & 1;
  const int lm = lane & 15, kg = lane >> 4;

  f32x4 acc[4][2] = {};
  const int aoffbase = (wm * 64 + lm) * LSTR + kg * 8;
  const int boffbase = (wn * 32 + lm) * LSTR + kg * 8;

  for (int kt = 0; kt < 3; ++kt) {
    #pragma unroll
    for (int i = 0; i < 4; ++i) {
      int c = tid + i * 256;
      int row = c >> 3, cc = (c & 7) * 8;
      *(uint4*)(As + row * LSTR + cc) =
          *(const uint4*)(Ag + (size_t)(mt * 128 + row) * 192 + kt * 64 + cc);
    }
    #pragma unroll
    for (int i = 0; i < 2; ++i) {
      int c = tid + i * 256;
      int row = c >> 3, cc = (c & 7) * 8;
      size_t src = (size_t)(nt * 64 + row) * 192 + kt * 64 + cc;
      *(uint4*)(Bh + row * LSTR + cc) = *(const uint4*)(Wh + src);
      *(uint4*)(Bl + row * LSTR + cc) = *(const uint4*)(Wl + src);
    }
    __syncthreads();
    #pragma unroll
    for (int ks = 0; ks < 2; ++ks) {
      bf16x8 bh_[2], bl_[2];
      #pragma unroll
      for (int nf = 0; nf < 2; ++nf) {
        bh_[nf] = *(const bf16x8*)(Bh + boffbase + nf * 16 * LSTR + ks * 32);
        bl_[nf] = *(const bf16x8*)(Bl + boffbase + nf * 16 * LSTR + ks * 32);
      }
      #pragma unroll
      for (int mf = 0; mf < 4; ++mf) {
        bf16x8 af = *(const bf16x8*)(As + aoffbase + mf * 16 * LSTR + ks * 32);
        #pragma unroll
        for (int nf = 0; nf < 2; ++nf) {
          acc[mf][nf] = __builtin_amdgcn_mfma_f32_16x16x32_bf16(af, bh_[nf], acc[mf][nf], 0, 0, 0);
          acc[mf][nf] = __builtin_amdgcn_mfma_f32_16x16x32_bf16(af, bl_[nf], acc[mf][nf], 0, 0, 0);
        }
      }
    }
    __syncthreads();
  }

  #pragma unroll
  for (int mf = 0; mf < 4; ++mf) {
    int m0 = mt * 128 + wm * 64 + mf * 16 + kg * 4;
    #pragma unroll
    for (int nf = 0; nf < 2; ++nf) {
      int col = nt * 64 + wn * 32 + nf * 16 + lm;
      float bias = biasg[col];
      #pragma unroll
      for (int r = 0; r < 4; ++r)
        og[(size_t)(m0 + r) * 192 + col] = acc[mf][nf][r] + bias;
    }
  }
}

// ---------------------------------------------------------------------------
// agent pooling, vectorized
// ---------------------------------------------------------------------------
__global__ __launch_bounds__(256) void k_pool(const u16* __restrict__ qg, u16* __restrict__ agg)
{
  int idx = blockIdx.x * 256 + threadIdx.x;
  int d8 = idx & 3;
  int a = (idx >> 2) % 49;
  int bh = idx / (49 * 4);
  int py = a / 7, px = a - py * 7;
  int n0 = (py * 2) * 14 + px * 2;
  const u16* qb = qg + (size_t)bh * 196 * 32 + d8 * 8;
  uint4 r0 = *(const uint4*)(qb + n0 * 32);
  uint4 r1 = *(const uint4*)(qb + (n0 + 1) * 32);
  uint4 r2 = *(const uint4*)(qb + (n0 + 14) * 32);
  uint4 r3 = *(const uint4*)(qb + (n0 + 15) * 32);
  const u16 *p0 = (const u16*)&r0, *p1 = (const u16*)&r1, *p2 = (const u16*)&r2, *p3 = (const u16*)&r3;
  u16 o[8];
  #pragma unroll
  for (int j = 0; j < 8; ++j)
    o[j] = f2bf(0.25f * (bf2f(p0[j]) + bf2f(p1[j]) + bf2f(p2[j]) + bf2f(p3[j])));
  *(uint4*)(agg + (size_t)idx * 8) = pack8(o);
}

// ---------------------------------------------------------------------------
// bias precompute (pre-scaled by LOG2E for exp2-softmax) + qkv_w f32->bf16
// + proj_w f32 -> bf16 hi/lo pair
// ---------------------------------------------------------------------------
__device__ __forceinline__ void lerpw(int i, int& j0, int& j1, float& f) {
  float xx = 0.5f * i - 0.25f;
  int j = (int)floorf(xx);
  f = xx - j;
  if (j < 0) { j = 0; f = 0.f; }
  j0 = j;
  j1 = (j + 1 > 6) ? 6 : j + 1;
}
__device__ __forceinline__ float bilin7(const float* src, int y, int x) {
  int y0, y1, x0, x1; float fy, fx;
  lerpw(y, y0, y1, fy); lerpw(x, x0, x1, fx);
  float v00 = src[y0 * 7 + x0], v01 = src[y0 * 7 + x1];
  float v10 = src[y1 * 7 + x0], v11 = src[y1 * 7 + x1];
  return (1.f - fy) * ((1.f - fx) * v00 + fx * v01) + fy * ((1.f - fx) * v10 + fx * v11);
}
__global__ __launch_bounds__(256) void k_bias(
    const float* __restrict__ an_, const float* __restrict__ na_,
    const float* __restrict__ ah_, const float* __restrict__ aw_,
    const float* __restrict__ ha_, const float* __restrict__ wa_,
    const float* __restrict__ qw_, const float* __restrict__ pw_,
    float* __restrict__ b1, float* __restrict__ b2, u16* __restrict__ wq,
    u16* __restrict__ wph, u16* __restrict__ wpl)
{
  int i = blockIdx.x * 256 + threadIdx.x;
  const int T1 = 6 * 49 * 208;
  const int T2 = 6 * 196 * 64;
  const int T3 = 576 * 192;
  const int T4 = 192 * 192;
  if (i < T1) {
    int n = i % 208, a = (i / 208) % 49, h = i / (208 * 49);
    float v = 0.f;
    if (n < 196) {
      int y = n / 14, x = n - y * 14;
      v = bilin7(an_ + (h * 49 + a) * 49, y, x)
        + ah_[(h * 49 + a) * 14 + y] + aw_[(h * 49 + a) * 14 + x];
    }
    b1[i] = v * LOG2E;
  } else if (i < T1 + T2) {
    int j = i - T1;
    int a = j & 63, n = (j >> 6) % 196, h = j / (196 * 64);
    float v = 0.f;
    if (a < 49) {
      int y = n / 14, x = n - y * 14;
      v = bilin7(na_ + (h * 49 + a) * 49, y, x)
        + ha_[(h * 14 + y) * 49 + a] + wa_[(h * 14 + x) * 49 + a];
    }
    b2[j] = v * LOG2E;
  } else if (i < T1 + T2 + T3) {
    int j = i - T1 - T2;
    wq[j] = f2bf(qw_[j]);
  } else if (i < T1 + T2 + T3 + T4) {
    int j = i - T1 - T2 - T3;
    float w = pw_[j];
    u16 hi = f2bf(w);
    wph[j] = hi;
    wpl[j] = f2bf(w - bf2f(hi));
  }
}

// ---------------------------------------------------------------------------
// MFMA attention + fused depthwise conv. No-max exp2 softmax (scores bounded,
// softmax shift-invariant; biases pre-scaled by LOG2E), normalize-after-MFMA,
// f16 vrm conv, PSTR 216, (256,4).
// ---------------------------------------------------------------------------
#define PSTR 216  // vt row stride in u16
#define QSTR 72   // avt row stride
#define VSTR 40   // vrm row stride in u16 (80B, 16B-aligned rows)

__global__ __launch_bounds__(256, 4) void k_attn(
    const u16* __restrict__ qg, const u16* __restrict__ kgl, const u16* __restrict__ vgl,
    const u16* __restrict__ agg, const float* __restrict__ b1p, const float* __restrict__ b2p,
    const float* __restrict__ dwcw, const float* __restrict__ dwcb,
    u16* __restrict__ preg)
{
  __shared__ __align__(16) u16 vt[32 * PSTR];    // 13824 B : V^T bf16, cols 196..207 zero
  __shared__ __align__(16) u16 vrm[196 * VSTR];  // 15680 B : V [n][d] as f16
  __shared__ __align__(16) u16 avt[32 * QSTR];   //  4608 B : AV^T [d][a]
  __shared__ __align__(16) float wdl[320];       //  1280 B : [tap][32] weights + [32] bias

  const int bh = blockIdx.x, h = bh % 6, b = bh / 6;
  const int tid = threadIdx.x, lane = tid & 63, w = tid >> 6;
  const int lm = lane & 15, kg = lane >> 4;
  const size_t base = (size_t)bh * (196 * 32);

  // ---- stage V: row-major f16 (b128 writes) + bf16 transpose (scalar) ----
  for (int c = tid; c < 784; c += 256) {
    int row = c >> 2, d0 = (c & 3) * 8;
    uint4 vv = *(const uint4*)(vgl + base + row * 32 + d0);
    const u16* pv = (const u16*)&vv;
    u16 hf[8];
    #pragma unroll
    for (int j = 0; j < 8; ++j) {
      vt[(d0 + j) * PSTR + row] = pv[j];
      hf[j] = f2h(bf2f(pv[j]));
    }
    *(uint4*)(vrm + row * VSTR + d0) = pack8(hf);
  }
  // zero vt cols 196..207 (dw 98..103) of each of 32 rows
  for (int c = tid; c < 192; c += 256) {
    int row = c / 6, col = 98 + c % 6;
    ((unsigned*)vt)[row * (PSTR / 2) + col] = 0;
  }
  // conv weights, transposed layout: wdl[tap*32 + d] ; bias at wdl[288 + d]
  for (int c = tid; c < 320; c += 256) {
    if (c < 288) {
      int tap = c >> 5, d = c & 31;
      wdl[tap * 32 + d] = dwcw[h * 288 + d * 9 + tap];
    } else {
      wdl[c] = dwcb[h * 32 + (c - 288)];
    }
  }

  // ---- ag fragment for p1 (this wave's agent block) ----
  const size_t agbase = (size_t)bh * 49 * 32;
  bf16x8 agw;
  {
    int a = 16 * w + lm;
    agw = (a < 49) ? *(const bf16x8*)(agg + agbase + a * 32 + kg * 8) : zfrag();
  }

  // ---- p1: S1[n][a] via direct-global K fragments ----
  f32x4 acc1[13];
  #pragma unroll
  for (int t = 0; t < 13; ++t) {
    bf16x8 afr = *(const bf16x8*)(kgl + base + (16 * t + lm) * 32 + kg * 8);
    acc1[t] = __builtin_amdgcn_mfma_f32_16x16x32_bf16(afr, agw, (f32x4){0.f, 0.f, 0.f, 0.f}, 0, 0, 0);
  }

  // ---- sm1: no-max exp2 softmax; pack UNNORMALIZED e ----
  const int arow = 16 * w + lm;
  uint2 p1pk[13];
  float inv1;
  {
    const float* b1base = b1p + ((size_t)(h * 49 + arow) * 208 + 4 * kg);
    #pragma unroll
    for (int t = 0; t < 13; ++t) {
      f32x4 bv = (arow < 49) ? *(const f32x4*)(b1base + 16 * t) : (f32x4){0.f, 0.f, 0.f, 0.f};
      #pragma unroll
      for (int r = 0; r < 4; ++r) acc1[t][r] = acc1[t][r] * SCALE2 + bv[r];
    }
    float sum = 0.f;
    #pragma unroll
    for (int t = 0; t < 13; ++t) {
      #pragma unroll
      for (int r = 0; r < 4; ++r) {
        float e = (t < 12 || kg == 0) ? fexp2(acc1[t][r]) : 0.f;
        acc1[t][r] = e; sum += e;
      }
    }
    sum += __shfl_xor(sum, 16);
    sum += __shfl_xor(sum, 32);
    inv1 = 1.0f / sum;
    #pragma unroll
    for (int t = 0; t < 13; ++t)
      p1pk[t] = pk4(acc1[t][0], acc1[t][1], acc1[t][2], acc1[t][3]);
  }

  __syncthreads();   // bar1: vt/vrm/wdl staged (p1+sm1 overlapped with staging)

  // ---- p2: AV[a][d] = sum_n P1[a][n]·V[n][d]; A-frags via intra-wave shfl ----
  f32x4 accav[2] = {{0.f, 0.f, 0.f, 0.f}, {0.f, 0.f, 0.f, 0.f}};
  const int sl = (lane & 15) | (((2 * kg) & 3) << 4);
  const int sh = (lane & 15) | (((2 * kg + 1) & 3) << 4);
  #pragma unroll
  for (int kt = 0; kt < 6; ++kt) {
    uint2 e0 = shfl_u2(p1pk[2 * kt], sl);
    uint2 e1 = shfl_u2(p1pk[2 * kt + 1], sl);
    uint2 o0 = shfl_u2(p1pk[2 * kt], sh);
    uint2 o1 = shfl_u2(p1pk[2 * kt + 1], sh);
    uint2 lo = (kg & 2) ? e1 : e0;
    uint2 hi = (kg & 2) ? o1 : o0;
    union { uint4 u; bf16x8 v; } a_;
    a_.u = make_uint4(lo.x, lo.y, hi.x, hi.y);
    #pragma unroll
    for (int nt = 0; nt < 2; ++nt) {
      bf16x8 bfr = *(const bf16x8*)(vt + (16 * nt + lm) * PSTR + kt * 32 + kg * 8);
      accav[nt] = __builtin_amdgcn_mfma_f32_16x16x32_bf16(a_.v, bfr, accav[nt], 0, 0, 0);
    }
  }
  {
    union { uint4 u; bf16x8 v; } a_;
    a_.u = make_uint4(p1pk[12].x, p1pk[12].y, 0u, 0u);
    #pragma unroll
    for (int nt = 0; nt < 2; ++nt) {
      uint2 vv = *(const uint2*)(vt + (16 * nt + lm) * PSTR + 192 + kg * 4);
      union { uint4 u; bf16x8 v; } b_;
      b_.u = make_uint4(vv.x, vv.y, 0u, 0u);
      accav[nt] = __builtin_amdgcn_mfma_f32_16x16x32_bf16(a_.v, b_.v, accav[nt], 0, 0, 0);
    }
  }

  // normalize after p2: accav rows are a = 16w + 4kg + r; inv lives at lane lm=4kg+r
  float si[4];
  #pragma unroll
  for (int r = 0; r < 4; ++r) si[r] = __shfl(inv1, kg * 4 + r);

  // AV^T to LDS (cross-wave redistribution for p4)
  #pragma unroll
  for (int nt = 0; nt < 2; ++nt)
    *(uint2*)(avt + (16 * nt + lm) * QSTR + 16 * w + 4 * kg) =
        pk4(accav[nt][0] * si[0], accav[nt][1] * si[1],
            accav[nt][2] * si[2], accav[nt][3] * si[3]);

  // ---- Q and AG fragments for the i-loop ----
  bf16x8 qf[4];
  #pragma unroll
  for (int i = 0; i < 4; ++i) {
    int nt = w + 4 * i;
    int row = 16 * nt + lm;
    if (nt < 13 && row < 196)
      qf[i] = *(const bf16x8*)(qg + base + row * 32 + kg * 8);
    else
      qf[i] = zfrag();
  }
  bf16x8 agf[4];
  #pragma unroll
  for (int mt = 0; mt < 4; ++mt) {
    int a = 16 * mt + lm;
    if (a < 49) agf[mt] = *(const bf16x8*)(agg + agbase + a * 32 + kg * 8);
    else agf[mt] = zfrag();
  }

  __syncthreads();   // bar2: avt visible to all waves

  // ---- per n-tile: p3 (S2^T) + sm2 + shfl-exchange + p4 + dwconv + store ----
  #pragma unroll
  for (int i = 0; i < 4; ++i) {
    int nt = w + 4 * i;
    if (nt < 13) {
      const int ncol = 16 * nt + lm;
      f32x4 acc2[4];
      #pragma unroll
      for (int mt = 0; mt < 4; ++mt)
        acc2[mt] = __builtin_amdgcn_mfma_f32_16x16x32_bf16(agf[mt], qf[i], (f32x4){0.f, 0.f, 0.f, 0.f}, 0, 0, 0);
      const float* b2base = b2p + ((size_t)(h * 196 + (ncol < 196 ? ncol : 0)) * 64 + 4 * kg);
      #pragma unroll
      for (int mt = 0; mt < 4; ++mt) {
        f32x4 bv = (ncol < 196) ? *(const f32x4*)(b2base + 16 * mt) : (f32x4){0.f, 0.f, 0.f, 0.f};
        #pragma unroll
        for (int r = 0; r < 4; ++r) acc2[mt][r] = acc2[mt][r] * SCALE2 + bv[r];
      }
      float sum = 0.f;
      #pragma unroll
      for (int mt = 0; mt < 4; ++mt) {
        #pragma unroll
        for (int r = 0; r < 4; ++r) {
          bool valid = (mt < 3) || (kg == 0 && r == 0);
          float e = valid ? fexp2(acc2[mt][r]) : 0.f;
          acc2[mt][r] = e; sum += e;
        }
      }
      sum += __shfl_xor(sum, 16);
      sum += __shfl_xor(sum, 32);
      const float inv = 1.0f / sum;   // applied after p4 (lane owns ncol)
      uint2 p2pk[4];
      #pragma unroll
      for (int mt = 0; mt < 4; ++mt)
        p2pk[mt] = pk4(acc2[mt][0], acc2[mt][1], acc2[mt][2], acc2[mt][3]);

      // p4: out^T[d][ncol] = sum_a AVt[d][a]·P2[a][ncol]
      f32x4 acc4[2] = {{0.f, 0.f, 0.f, 0.f}, {0.f, 0.f, 0.f, 0.f}};
      #pragma unroll
      for (int kt = 0; kt < 2; ++kt) {
        uint2 e0 = shfl_u2(p2pk[2 * kt], sl);
        uint2 e1 = shfl_u2(p2pk[2 * kt + 1], sl);
        uint2 o0 = shfl_u2(p2pk[2 * kt], sh);
        uint2 o1 = shfl_u2(p2pk[2 * kt + 1], sh);
        uint2 lo = (kg & 2) ? e1 : e0;
        uint2 hi = (kg & 2) ? o1 : o0;
        union { uint4 u; bf16x8 v; } b_;
        b_.u = make_uint4(lo.x, lo.y, hi.x, hi.y);
        #pragma unroll
        for (int mt2 = 0; mt2 < 2; ++mt2) {
          bf16x8 afr = *(const bf16x8*)(avt + (16 * mt2 + lm) * QSTR + kt * 32 + kg * 8);
          acc4[mt2] = __builtin_amdgcn_mfma_f32_16x16x32_bf16(afr, b_.v, acc4[mt2], 0, 0, 0);
        }
      }
      if (ncol < 196) {
        // ---- fused depthwise 3x3 conv: f16 vrm reads -> fma_mix, f32 accum ----
        const int y = ncol / 14, x = ncol - y * 14;
        float dw[2][4];
        #pragma unroll
        for (int mt = 0; mt < 2; ++mt) {
          f32x4 bv = *(const f32x4*)(wdl + 288 + 16 * mt + 4 * kg);
          #pragma unroll
          for (int r = 0; r < 4; ++r) dw[mt][r] = bv[r];
        }
        #pragma unroll
        for (int ky = 0; ky < 3; ++ky) {
          int yy = y + ky - 1;
          if (yy < 0 || yy > 13) continue;
          #pragma unroll
          for (int kx = 0; kx < 3; ++kx) {
            int xx = x + kx - 1;
            if (xx < 0 || xx > 13) continue;
            int nv = yy * 14 + xx;
            int tap = ky * 3 + kx;
            #pragma unroll
            for (int mt = 0; mt < 2; ++mt) {
              f32x4 wv = *(const f32x4*)(wdl + tap * 32 + 16 * mt + 4 * kg);
              const __half2* hv = (const __half2*)(vrm + nv * VSTR + 16 * mt + 4 * kg);
              __half2 h0 = hv[0], h1 = hv[1];
              dw[mt][0] += wv[0] * __low2float(h0);
              dw[mt][1] += wv[1] * __high2float(h0);
              dw[mt][2] += wv[2] * __low2float(h1);
              dw[mt][3] += wv[3] * __high2float(h1);
            }
          }
        }
        u16* orow = preg + ((size_t)b * 196 + ncol) * 192 + h * 32;
        #pragma unroll
        for (int mt = 0; mt < 2; ++mt)
          *(uint2*)(orow + 16 * mt + 4 * kg) =
              pk4(acc4[mt][0] * inv + dw[mt][0], acc4[mt][1] * inv + dw[mt][1],
                  acc4[mt][2] * inv + dw[mt][2], acc4[mt][3] * inv + dw[mt][3]);
      }
    }
  }
}

// ---------------------------------------------------------------------------
extern "C" void kernel_launch(void* const* d_in, const int* in_sizes, int n_in,
                              void* d_out, int out_size, void* d_ws, size_t ws_size,
                              hipStream_t stream)
{
  (void)in_sizes; (void)n_in; (void)out_size;
  const float* x      = (const float*)d_in[0];
  const float* qkv_w  = (const float*)d_in[1];
  const float* qkv_b  = (const float*)d_in[2];
  const float* proj_w = (const float*)d_in[3];
  const float* proj_b = (const float*)d_in[4];
  const float* dwc_w  = (const float*)d_in[5];
  const float* dwc_b  = (const float*)d_in[6];
  const float* an_b   = (const float*)d_in[7];
  const float* na_b   = (const float*)d_in[8];
  const float* ah_b   = (const float*)d_in[9];
  const float* aw_b   = (const float*)d_in[10];
  const float* ha_b   = (const float*)d_in[11];
  const float* wa_b   = (const float*)d_in[12];

  const size_t SZ_QKV = (size_t)512 * 6 * 196 * 32 * 2;   // bf16
  const size_t SZ_AG  = (size_t)512 * 6 * 49 * 32 * 2;
  const size_t SZ_B1  = (((size_t)6 * 49 * 208 * 4) + 255) & ~(size_t)255;
  const size_t SZ_B2  = (size_t)6 * 196 * 64 * 4;
  const size_t SZ_WQ  = (((size_t)576 * 192 * 2) + 255) & ~(size_t)255;
  const size_t SZ_WP  = (((size_t)192 * 192 * 2) + 255) & ~(size_t)255;

  char* ws = (char*)d_ws;
  u16*   qb    = (u16*)(ws);
  u16*   kb    = (u16*)(ws + SZ_QKV);
  u16*   vb    = (u16*)(ws + 2 * SZ_QKV);
  u16*   agb   = (u16*)(ws + 3 * SZ_QKV);
  float* b1    = (float*)(ws + 3 * SZ_QKV + SZ_AG);
  float* b2    = (float*)(ws + 3 * SZ_QKV + SZ_AG + SZ_B1);
  u16*   preb  = (u16*)(ws + 3 * SZ_QKV + SZ_AG + SZ_B1 + SZ_B2);
  u16*   wqb   = (u16*)(ws + 3 * SZ_QKV + SZ_AG + SZ_B1 + SZ_B2 + SZ_QKV);
  u16*   wph   = (u16*)(ws + 3 * SZ_QKV + SZ_AG + SZ_B1 + SZ_B2 + SZ_QKV + SZ_WQ);
  u16*   wpl   = (u16*)(ws + 3 * SZ_QKV + SZ_AG + SZ_B1 + SZ_B2 + SZ_QKV + SZ_WQ + SZ_WP);

  const size_t need = 3 * SZ_QKV + SZ_AG + SZ_B1 + SZ_B2 + SZ_QKV + SZ_WQ + 2 * SZ_WP;
  if (ws_size < need) return;

  const int TOT = 6 * 49 * 208 + 6 * 196 * 64 + 576 * 192 + 192 * 192;
  k_bias<<<(TOT + 255) / 256, 256, 0, stream>>>(an_b, na_b, ah_b, aw_b, ha_b, wa_b,
                                                qkv_w, proj_w, b1, b2, wqb, wph, wpl);
  k_qkv<<<1568 * 3, 256, 0, stream>>>(x, wqb, qkv_b, qb, kb, vb);
  k_pool<<<2352, 256, 0, stream>>>(qb, agb);
  k_attn<<<3072, 256, 0, stream>>>(qb, kb, vb, agb, b1, b2, dwc_w, dwc_b, preb);
  k_proj<<<784 * 3, 256, 0, stream>>>(preb, wph, wpl, proj_b, (float*)d_out);
}